// Round 1
// baseline (106.293 us; speedup 1.0000x reference)
//
#include <hip/hip_runtime.h>

typedef float2 cplx;

__device__ __forceinline__ cplx cmul(cplx a, cplx b){
  return make_float2(a.x*b.x - a.y*b.y, a.x*b.y + a.y*b.x);
}
__device__ __forceinline__ cplx cadd(cplx a, cplx b){
  return make_float2(a.x + b.x, a.y + b.y);
}

// ======================= setup kernel =======================
// Builds the 7 fused conv 4x4 matrices (with U3 pooling gates merged in).
// Basis for conv(wq,wp): k = 2*bit_q + bit_p. M maps old state -> new state.
// Column j of M = gate sequence applied to basis state e_j.

__device__ __forceinline__ void rz_gate(cplx* st, float t, int bmask){
  float s, c;
  sincosf(0.5f*t, &s, &c);
  cplx em = make_float2(c, -s);  // bit=0: exp(-i t/2)
  cplx ep = make_float2(c,  s);  // bit=1: exp(+i t/2)
  for(int k=0;k<4;k++) st[k] = cmul(st[k], (k & bmask) ? ep : em);
}
__device__ __forceinline__ void ry_gate_q(cplx* st, float t){
  float s, c;
  sincosf(0.5f*t, &s, &c);
  for(int bp=0;bp<2;bp++){
    cplx a0 = st[bp], a1 = st[2+bp];
    st[bp]   = make_float2(c*a0.x - s*a1.x, c*a0.y - s*a1.y);
    st[2+bp] = make_float2(s*a0.x + c*a1.x, s*a0.y + c*a1.y);
  }
}
__device__ __forceinline__ void u3_gate(cplx* st, const float* p, int onq){
  float th = p[0], ph = p[1], la = p[2];
  float ss, cc, sl, cl, sp, cp, spl, cpl;
  sincosf(0.5f*th, &ss, &cc);
  sincosf(la, &sl, &cl);
  sincosf(ph, &sp, &cp);
  sincosf(ph+la, &spl, &cpl);
  cplx u00 = make_float2(cc, 0.f);
  cplx u01 = make_float2(-cl*ss, -sl*ss);
  cplx u10 = make_float2( cp*ss,  sp*ss);
  cplx u11 = make_float2(cpl*cc, spl*cc);
  if(onq){
    for(int bp=0;bp<2;bp++){
      cplx a0 = st[bp], a1 = st[2+bp];
      st[bp]   = cadd(cmul(u00,a0), cmul(u01,a1));
      st[2+bp] = cadd(cmul(u10,a0), cmul(u11,a1));
    }
  } else {
    for(int bq=0;bq<2;bq++){
      cplx a0 = st[2*bq], a1 = st[2*bq+1];
      st[2*bq]   = cadd(cmul(u00,a0), cmul(u01,a1));
      st[2*bq+1] = cadd(cmul(u10,a0), cmul(u11,a1));
    }
  }
}

__global__ void setup_conv_kernel(const float* __restrict__ rz,
                                  const float* __restrict__ ry,
                                  const float* __restrict__ u3,
                                  cplx* __restrict__ M){
  int t = threadIdx.x;
  if(t >= 28) return;           // 7 convs x 4 columns
  int ci = t >> 2, col = t & 3;
  const float* rz3 = rz + 3*ci;
  const float* ry2 = ry + 2*ci;
  // merged U3 table: convs 0..3 get pooling U3 on wq (u3 idx = ci);
  // conv 5 (7,5) gets final U3(7)=u3[5] on wq; conv 6 (5,3) gets final
  // U3(3)=u3[4] on wp; conv 4 (3,1) gets none.
  int u3slot = 0, u3idx = 0;    // 0=none, 1=wq, 2=wp
  if(ci <= 3){ u3slot = 1; u3idx = ci; }
  else if(ci == 5){ u3slot = 1; u3idx = 5; }
  else if(ci == 6){ u3slot = 2; u3idx = 4; }

  cplx st[4];
  for(int k=0;k<4;k++) st[k] = make_float2(k==col ? 1.f : 0.f, 0.f);
  // RZ(q) CNOT(q->p) RZ(p) RY(q) CNOT(p->q) RY(q) CNOT(q->p) RZ(p)
  rz_gate(st, rz3[0], 2);
  { cplx tmp = st[2]; st[2] = st[3]; st[3] = tmp; }   // CNOT q->p: swap 2,3
  rz_gate(st, rz3[1], 1);
  ry_gate_q(st, ry2[0]);
  { cplx tmp = st[1]; st[1] = st[3]; st[3] = tmp; }   // CNOT p->q: swap 1,3
  ry_gate_q(st, ry2[1]);
  { cplx tmp = st[2]; st[2] = st[3]; st[3] = tmp; }   // CNOT q->p
  rz_gate(st, rz3[2], 1);
  if(u3slot == 1)      u3_gate(st, u3 + 3*u3idx, 1);
  else if(u3slot == 2) u3_gate(st, u3 + 3*u3idx, 0);
  for(int k=0;k<4;k++) M[ci*16 + k*4 + col] = st[k];
}

// ======================= main kernel =======================
// One wave (64 lanes) per batch element. Amplitude index i = r*64 + lane,
// r in [0,4): register bits = i[7:6] = wires 0,1; lane bits = i[5:0] = wires 2..7.

__device__ __forceinline__ cplx sxc(cplx a, int m){
  if(m == 0) return a;
  return make_float2(__shfl_xor(a.x, m, 64), __shfl_xor(a.y, m, 64));
}

// rxx on a wire pair: new = c*psi[i] - i*s*psi[i^mask]; mask = MR*64 + ML
template<int MR, int ML>
__device__ __forceinline__ void rxx_apply(cplx* v, float c, float s){
  cplx p[4];
  #pragma unroll
  for(int r=0;r<4;r++) p[r] = sxc(v[r ^ MR], ML);
  #pragma unroll
  for(int r=0;r<4;r++)
    v[r] = make_float2(c*v[r].x + s*p[r].y, c*v[r].y - s*p[r].x);
}

// fused 4x4 conv on wires (wq,wp): q xor-mask = MRQ*64+MLQ, p = MRP*64+MLPP
template<int MRQ, int MLQ, int MRP, int MLPP>
__device__ __forceinline__ void conv_apply(cplx* v, const cplx* M, int lane){
  cplx pq[4], pp[4], pb[4];
  #pragma unroll
  for(int r=0;r<4;r++) pq[r] = sxc(v[r ^ MRQ], MLQ);
  #pragma unroll
  for(int r=0;r<4;r++) pp[r] = sxc(v[r ^ MRP], MLPP);
  #pragma unroll
  for(int r=0;r<4;r++) pb[r] = sxc(v[r ^ (MRQ^MRP)], MLQ^MLPP);
  cplx nv[4];
  #pragma unroll
  for(int r=0;r<4;r++){
    int i = r*64 + lane;
    int k = ((i & (MRQ*64 + MLQ)) ? 2 : 0) | ((i & (MRP*64 + MLPP)) ? 1 : 0);
    const cplx* row = M + k*4;
    cplx acc = cmul(row[k],   v[r]);
    acc = cadd(acc, cmul(row[k^1], pp[r]));
    acc = cadd(acc, cmul(row[k^2], pq[r]));
    acc = cadd(acc, cmul(row[k^3], pb[r]));
    nv[r] = acc;
  }
  #pragma unroll
  for(int r=0;r<4;r++) v[r] = nv[r];
}

__global__ void __launch_bounds__(256) qcnn_kernel(
    const float* __restrict__ theta, const float* __restrict__ phi,
    const cplx* __restrict__ Mg,
    const float* __restrict__ w1, const float* __restrict__ b1,
    const float* __restrict__ w2, const float* __restrict__ b2,
    float* __restrict__ out){
  __shared__ cplx M[112];
  int tid = threadIdx.x;
  if(tid < 112) M[tid] = Mg[tid];
  __syncthreads();

  int lane = tid & 63;
  int b = blockIdx.x*4 + (tid >> 6);
  float th = theta[b], ph = phi[b];
  float c, s;
  __sincosf(th, &s, &c);      // rxx uses cos(theta), sin(theta)

  cplx v[4];
  #pragma unroll
  for(int r=0;r<4;r++) v[r] = make_float2(0.0625f, 0.f);  // H^8 |0>

  // zphase: exp(i*phi*(2*popc(i)-8)); popc(i)=popc(lane)+popc(r), popc(r) in {0,1,2}
  int popl = __popc(lane);
  float zc[3], zs[3];
  #pragma unroll
  for(int pr=0;pr<3;pr++){
    float ang = ph * (float)(2*(popl+pr) - 8);
    __sincosf(ang, &zs[pr], &zc[pr]);
  }

  for(int cyc=0;cyc<4;cyc++){
    #pragma unroll
    for(int r=0;r<4;r++){
      int pr = __popc(r);
      float a = v[r].x, bb = v[r].y;
      v[r] = make_float2(a*zc[pr] - bb*zs[pr], a*zs[pr] + bb*zc[pr]);
    }
    // wire w -> amplitude bit (7-w); pair (w,w+1) mask = 3 << (6-w)
    rxx_apply<3,0 >(v, c, s);   // (0,1): bits 7,6 -> registers
    rxx_apply<0,48>(v, c, s);   // (2,3)
    rxx_apply<0,12>(v, c, s);   // (4,5)
    rxx_apply<0,3 >(v, c, s);   // (6,7)
    rxx_apply<1,32>(v, c, s);   // (1,2): bit6(reg) + bit5(lane)
    rxx_apply<0,24>(v, c, s);   // (3,4)
    rxx_apply<0,6 >(v, c, s);   // (5,6)
  }

  // fused convs (U3s merged in setup). Order: layer1 (disjoint), then
  // (3,1) and (7,5) before (5,3).
  conv_apply<1,0 ,2,0 >(v, M +  0, lane);  // (1,0) + U3(1)
  conv_apply<0,16,0,32>(v, M + 16, lane);  // (3,2) + U3(3)
  conv_apply<0,4 ,0,8 >(v, M + 32, lane);  // (5,4) + U3(5)
  conv_apply<0,1 ,0,2 >(v, M + 48, lane);  // (7,6) + U3(7)
  conv_apply<0,16,1,0 >(v, M + 64, lane);  // (3,1)
  conv_apply<0,1 ,0,4 >(v, M + 80, lane);  // (7,5) + final U3(7)
  conv_apply<0,4 ,0,16>(v, M + 96, lane);  // (5,3) + final U3(3)

  // <Z_3> (bit 4, a lane bit) and <Z_7> (bit 0, a lane bit)
  float p2 = 0.f;
  #pragma unroll
  for(int r=0;r<4;r++) p2 += v[r].x*v[r].x + v[r].y*v[r].y;
  float s3 = ((lane >> 4) & 1) ? -p2 : p2;
  float s7 = (lane & 1)        ? -p2 : p2;
  #pragma unroll
  for(int off=32; off>=1; off>>=1){
    s3 += __shfl_xor(s3, off, 64);
    s7 += __shfl_xor(s7, off, 64);
  }

  if(lane == 0){
    float acc = b2[0];
    #pragma unroll
    for(int j=0;j<10;j++){
      float hv = tanhf(s3*w1[2*j] + s7*w1[2*j+1] + b1[j]);
      acc += hv * w2[j];
    }
    out[b] = 1.f / (1.f + __expf(-acc));
  }
}

extern "C" void kernel_launch(void* const* d_in, const int* in_sizes, int n_in,
                              void* d_out, int out_size, void* d_ws, size_t ws_size,
                              hipStream_t stream) {
  const float* theta = (const float*)d_in[0];
  const float* phi   = (const float*)d_in[1];
  const float* rz    = (const float*)d_in[2];
  const float* ry    = (const float*)d_in[3];
  const float* u3    = (const float*)d_in[4];
  const float* w1    = (const float*)d_in[5];
  const float* b1    = (const float*)d_in[6];
  const float* w2    = (const float*)d_in[7];
  const float* b2    = (const float*)d_in[8];
  cplx* M = (cplx*)d_ws;   // 112 float2 = 896 B

  hipLaunchKernelGGL(setup_conv_kernel, dim3(1), dim3(32), 0, stream, rz, ry, u3, M);
  hipLaunchKernelGGL(qcnn_kernel, dim3(8192/4), dim3(256), 0, stream,
                     theta, phi, M, w1, b1, w2, b2, (float*)d_out);
}

// Round 2
// 93.572 us; speedup vs baseline: 1.1359x; 1.1359x over previous
//
#include <hip/hip_runtime.h>

typedef float2 cplx;

__device__ __forceinline__ cplx cmul(cplx a, cplx b){
  return make_float2(a.x*b.x - a.y*b.y, a.x*b.y + a.y*b.x);
}
__device__ __forceinline__ cplx cmad(cplx a, cplx b, cplx acc){  // acc + a*b
  return make_float2(acc.x + a.x*b.x - a.y*b.y, acc.y + a.x*b.y + a.y*b.x);
}

// ======================= setup kernel (unchanged, verified R1) =======================
__device__ __forceinline__ void rz_gate(cplx* st, float t, int bmask){
  float s, c; sincosf(0.5f*t, &s, &c);
  cplx em = make_float2(c, -s), ep = make_float2(c, s);
  for(int k=0;k<4;k++) st[k] = cmul(st[k], (k & bmask) ? ep : em);
}
__device__ __forceinline__ void ry_gate_q(cplx* st, float t){
  float s, c; sincosf(0.5f*t, &s, &c);
  for(int bp=0;bp<2;bp++){
    cplx a0 = st[bp], a1 = st[2+bp];
    st[bp]   = make_float2(c*a0.x - s*a1.x, c*a0.y - s*a1.y);
    st[2+bp] = make_float2(s*a0.x + c*a1.x, s*a0.y + c*a1.y);
  }
}
__device__ __forceinline__ void u3_gate(cplx* st, const float* p, int onq){
  float th=p[0], ph=p[1], la=p[2];
  float ss,cc,sl,cl,sp,cp,spl,cpl;
  sincosf(0.5f*th,&ss,&cc); sincosf(la,&sl,&cl); sincosf(ph,&sp,&cp); sincosf(ph+la,&spl,&cpl);
  cplx u00=make_float2(cc,0.f), u01=make_float2(-cl*ss,-sl*ss);
  cplx u10=make_float2(cp*ss,sp*ss), u11=make_float2(cpl*cc,spl*cc);
  if(onq){
    for(int bp=0;bp<2;bp++){
      cplx a0=st[bp], a1=st[2+bp];
      st[bp]   = cmad(u01,a1,cmul(u00,a0));
      st[2+bp] = cmad(u11,a1,cmul(u10,a0));
    }
  } else {
    for(int bq=0;bq<2;bq++){
      cplx a0=st[2*bq], a1=st[2*bq+1];
      st[2*bq]   = cmad(u01,a1,cmul(u00,a0));
      st[2*bq+1] = cmad(u11,a1,cmul(u10,a0));
    }
  }
}

__global__ void setup_conv_kernel(const float* __restrict__ rz,
                                  const float* __restrict__ ry,
                                  const float* __restrict__ u3,
                                  cplx* __restrict__ M){
  int t = threadIdx.x;
  if(t >= 28) return;
  int ci = t >> 2, col = t & 3;
  const float* rz3 = rz + 3*ci;
  const float* ry2 = ry + 2*ci;
  int u3slot = 0, u3idx = 0;
  if(ci <= 3){ u3slot = 1; u3idx = ci; }
  else if(ci == 5){ u3slot = 1; u3idx = 5; }
  else if(ci == 6){ u3slot = 2; u3idx = 4; }
  cplx st[4];
  for(int k=0;k<4;k++) st[k] = make_float2(k==col ? 1.f : 0.f, 0.f);
  rz_gate(st, rz3[0], 2);
  { cplx tmp=st[2]; st[2]=st[3]; st[3]=tmp; }
  rz_gate(st, rz3[1], 1);
  ry_gate_q(st, ry2[0]);
  { cplx tmp=st[1]; st[1]=st[3]; st[3]=tmp; }
  ry_gate_q(st, ry2[1]);
  { cplx tmp=st[2]; st[2]=st[3]; st[3]=tmp; }
  rz_gate(st, rz3[2], 1);
  if(u3slot == 1)      u3_gate(st, u3+3*u3idx, 1);
  else if(u3slot == 2) u3_gate(st, u3+3*u3idx, 0);
  for(int k=0;k<4;k++) M[ci*16 + k*4 + col] = st[k];
}

// ======================= main kernel =======================
// 16 amplitudes per lane, 16 lanes per element, 4 elements per wave.
// Amplitude i[7:0]; wire w <-> bit (7-w).
// Register index r[3:0] = i[7:4]  (wires 0,1,2,3 -> reg masks 8,4,2,1)
// Sublane s[3:0]: s0=wire4(i3), s1=wire5(i2), s2=wire6(i1), s3=wire7(i0)
//   -> lane xor masks: w4=1, w5=2, w6=4, w7=8
// DPP (VALU pipe): masks 1 (quad xor1), 2 (xor2), 3 (xor3), 8 (row_ror:8)
// ds_swizzle (LDS pipe): masks 4, 6, 10, 12

#define DPP_XOR1 0xB1   // quad_perm [1,0,3,2]
#define DPP_XOR2 0x4E   // quad_perm [2,3,0,1]
#define DPP_XOR3 0x1B   // quad_perm [3,2,1,0]
#define DPP_ROR8 0x128  // row_ror:8 == xor 8 within 16-lane row

template<int C>
__device__ __forceinline__ float xdpp(float x){
  return __builtin_bit_cast(float,
    __builtin_amdgcn_mov_dpp(__builtin_bit_cast(int, x), C, 0xF, 0xF, true));
}
template<int MASK>
__device__ __forceinline__ float xswz(float x){
  return __builtin_bit_cast(float,
    __builtin_amdgcn_ds_swizzle(__builtin_bit_cast(int, x), (MASK<<10) | 0x1F));
}

enum Sh { SH_DPP1, SH_DPP2, SH_DPP3, SH_ROR8, SH_SWZ4, SH_SWZ6, SH_SWZ10, SH_SWZ12 };

template<Sh S> __device__ __forceinline__ float shf(float x){
  if      constexpr(S==SH_DPP1)  return xdpp<DPP_XOR1>(x);
  else if constexpr(S==SH_DPP2)  return xdpp<DPP_XOR2>(x);
  else if constexpr(S==SH_DPP3)  return xdpp<DPP_XOR3>(x);
  else if constexpr(S==SH_ROR8)  return xdpp<DPP_ROR8>(x);
  else if constexpr(S==SH_SWZ4)  return xswz<4>(x);
  else if constexpr(S==SH_SWZ6)  return xswz<6>(x);
  else if constexpr(S==SH_SWZ10) return xswz<10>(x);
  else                           return xswz<12>(x);
}
template<Sh S> __device__ __forceinline__ cplx shc(cplx a){
  return make_float2(shf<S>(a.x), shf<S>(a.y));
}

// rxx: new = c*psi - i*s*partner  -> x' = c*x + s*p.y ; y' = c*y - s*p.x
template<int MR>
__device__ __forceinline__ void rxx_reg(cplx* v, float c, float s){
  #pragma unroll
  for(int r=0;r<16;r++){
    int q = r ^ MR;
    if(r > q) continue;
    cplx a = v[r], b = v[q];
    v[r] = make_float2(c*a.x + s*b.y, c*a.y - s*b.x);
    v[q] = make_float2(c*b.x + s*a.y, c*b.y - s*a.x);
  }
}
template<Sh S>
__device__ __forceinline__ void rxx_lane(cplx* v, float c, float s){
  #pragma unroll
  for(int r=0;r<16;r++){
    cplx p = shc<S>(v[r]);
    v[r] = make_float2(c*v[r].x + s*p.y, c*v[r].y - s*p.x);
  }
}
// pair (3,4): reg mask 1 + lane xor1
__device__ __forceinline__ void rxx_mix34(cplx* v, float c, float s){
  #pragma unroll
  for(int r=0;r<16;r+=2){
    cplx pa = shc<SH_DPP1>(v[r^1]);
    cplx pb = shc<SH_DPP1>(v[r]);
    cplx a = v[r], b = v[r^1];
    v[r]   = make_float2(c*a.x + s*pa.y, c*a.y - s*pa.x);
    v[r^1] = make_float2(c*b.x + s*pb.y, c*b.y - s*pb.x);
  }
}

// conv on two register wires: group {r, r^MP, r^MQ, r^MQ^MP} = columns 0..3
template<int MQ, int MP>
__device__ __forceinline__ void conv_reg(cplx* v, const cplx* __restrict__ M){
  #pragma unroll
  for(int r=0;r<16;r++){
    if((r & (MQ|MP)) != 0) continue;
    cplx a0=v[r], a1=v[r^MP], a2=v[r^MQ], a3=v[r^MQ^MP];
    v[r]        = cmad(M[3], a3, cmad(M[2], a2, cmad(M[1], a1, cmul(M[0], a0))));
    v[r^MP]     = cmad(M[7], a3, cmad(M[6], a2, cmad(M[5], a1, cmul(M[4], a0))));
    v[r^MQ]     = cmad(M[11],a3, cmad(M[10],a2, cmad(M[9], a1, cmul(M[8], a0))));
    v[r^MQ^MP]  = cmad(M[15],a3, cmad(M[14],a2, cmad(M[13],a1, cmul(M[12],a0))));
  }
}

// conv on two lane wires; k = 2*bit_q + bit_p (per-lane, r-independent)
template<Sh SQ, Sh SP, Sh SB>
__device__ __forceinline__ void conv_lane(cplx* v, const cplx* __restrict__ M, int k){
  cplx es = M[k*4 + k], ep = M[k*4 + (k^1)], eq = M[k*4 + (k^2)], eb = M[k*4 + (k^3)];
  #pragma unroll
  for(int r=0;r<16;r++){
    cplx pq = shc<SQ>(v[r]);
    cplx pp = shc<SP>(v[r]);
    cplx pb = shc<SB>(v[r]);
    v[r] = cmad(eb, pb, cmad(eq, pq, cmad(ep, pp, cmul(es, v[r]))));
  }
}

// conv (5,3): q = wire5 (lane s1, xor2 DPP), p = wire3 (reg bit 0)
__device__ __forceinline__ void conv_53(cplx* v, const cplx* __restrict__ M, int s1){
  int t = 2*s1, u = 2 - t;
  const cplx* r0 = M + t*4;        // row k = t   (held bp=0)
  const cplx* r1 = M + (t+1)*4;    // row k = t+1 (held bp=1)
  cplx e00=r0[t], e01=r0[t+1], e02=r0[u], e03=r0[u+1];
  cplx e10=r1[t], e11=r1[t+1], e12=r1[u], e13=r1[u+1];
  #pragma unroll
  for(int r=0;r<16;r+=2){
    cplx pv0 = shc<SH_DPP2>(v[r]);     // partner (q flipped) of bp=0
    cplx pv1 = shc<SH_DPP2>(v[r+1]);   // partner of bp=1
    cplx a0 = v[r], a1 = v[r+1];
    v[r]   = cmad(e03, pv1, cmad(e02, pv0, cmad(e01, a1, cmul(e00, a0))));
    v[r+1] = cmad(e13, pv1, cmad(e12, pv0, cmad(e11, a1, cmul(e10, a0))));
  }
}

__global__ void __launch_bounds__(256) qcnn_kernel(
    const float* __restrict__ theta, const float* __restrict__ phi,
    const cplx* __restrict__ Mg,
    const float* __restrict__ w1, const float* __restrict__ b1,
    const float* __restrict__ w2, const float* __restrict__ b2,
    float* __restrict__ out){
  int tid  = threadIdx.x;
  int s_   = tid & 15;                       // sublane within element (DPP-row aligned)
  int b    = blockIdx.x*16 + (tid >> 4);     // element id
  int s0 = s_&1, s1 = (s_>>1)&1, s2 = (s_>>2)&1, s3 = (s_>>3)&1;

  float th = theta[b], ph = phi[b];
  float c, s;
  __sincosf(th, &s, &c);

  cplx v[16];
  #pragma unroll
  for(int r=0;r<16;r++) v[r] = make_float2(0.0625f, 0.f);   // H^8 |0>

  // zphase factors: cis(phi*(2*(popc(s)+popc(r)) - 8)), popc(r) in 0..4
  cplx zp[5];
  {
    int base = __popc(s_);
    float a0 = ph * (float)(2*base - 8);
    float sa, ca, s2p, c2p;
    __sincosf(a0, &sa, &ca);
    __sincosf(2.f*ph, &s2p, &c2p);
    cplx step = make_float2(c2p, s2p);
    zp[0] = make_float2(ca, sa);
    #pragma unroll
    for(int j=1;j<5;j++) zp[j] = cmul(zp[j-1], step);
  }

  #pragma unroll 1
  for(int cyc=0;cyc<4;cyc++){
    #pragma unroll
    for(int r=0;r<16;r++) v[r] = cmul(v[r], zp[__popc(r)]);
    // even pairs
    rxx_reg<12>(v, c, s);          // (0,1): reg bits 3,2
    rxx_reg<3>(v, c, s);           // (2,3): reg bits 1,0
    rxx_lane<SH_DPP3>(v, c, s);    // (4,5): lane mask 3
    rxx_lane<SH_SWZ12>(v, c, s);   // (6,7): lane mask 12
    // odd pairs
    rxx_reg<6>(v, c, s);           // (1,2): reg bits 2,1
    rxx_mix34(v, c, s);            // (3,4): reg bit0 + lane bit0
    rxx_lane<SH_SWZ6>(v, c, s);    // (5,6): lane mask 6
  }

  // convs (U3s folded in by setup kernel)
  conv_reg<4,8>(v, Mg +  0);                                  // (1,0)
  conv_reg<1,2>(v, Mg + 16);                                  // (3,2)
  conv_lane<SH_DPP2,SH_DPP1,SH_DPP3>(v, Mg + 32, 2*s1 + s0);  // (5,4)
  conv_lane<SH_ROR8,SH_SWZ4,SH_SWZ12>(v, Mg + 48, 2*s3 + s2); // (7,6)
  conv_reg<1,4>(v, Mg + 64);                                  // (3,1)
  conv_lane<SH_ROR8,SH_DPP2,SH_SWZ10>(v, Mg + 80, 2*s3 + s1); // (7,5)
  conv_53(v, Mg + 96, s1);                                    // (5,3)

  // <Z_3> = sign from r bit0 ; <Z_7> = sign from s bit3
  float tot = 0.f, z3 = 0.f;
  #pragma unroll
  for(int r=0;r<16;r++){
    float m = v[r].x*v[r].x + v[r].y*v[r].y;
    tot += m;
    z3 += (r & 1) ? -m : m;
  }
  float z7 = (s_ & 8) ? -tot : tot;
  // xor-reduce over the 16 lanes of this element
  z3 += xdpp<DPP_XOR1>(z3);  z7 += xdpp<DPP_XOR1>(z7);
  z3 += xdpp<DPP_XOR2>(z3);  z7 += xdpp<DPP_XOR2>(z7);
  z3 += xswz<4>(z3);         z7 += xswz<4>(z7);
  z3 += xdpp<DPP_ROR8>(z3);  z7 += xdpp<DPP_ROR8>(z7);

  if(s_ == 0){
    float acc = b2[0];
    #pragma unroll
    for(int j=0;j<10;j++){
      float hv = tanhf(z3*w1[2*j] + z7*w1[2*j+1] + b1[j]);
      acc += hv * w2[j];
    }
    out[b] = 1.f / (1.f + __expf(-acc));
  }
}

extern "C" void kernel_launch(void* const* d_in, const int* in_sizes, int n_in,
                              void* d_out, int out_size, void* d_ws, size_t ws_size,
                              hipStream_t stream) {
  const float* theta = (const float*)d_in[0];
  const float* phi   = (const float*)d_in[1];
  const float* rz    = (const float*)d_in[2];
  const float* ry    = (const float*)d_in[3];
  const float* u3    = (const float*)d_in[4];
  const float* w1    = (const float*)d_in[5];
  const float* b1    = (const float*)d_in[6];
  const float* w2    = (const float*)d_in[7];
  const float* b2    = (const float*)d_in[8];
  cplx* M = (cplx*)d_ws;   // 112 cplx = 896 B

  hipLaunchKernelGGL(setup_conv_kernel, dim3(1), dim3(32), 0, stream, rz, ry, u3, M);
  hipLaunchKernelGGL(qcnn_kernel, dim3(8192/16), dim3(256), 0, stream,
                     theta, phi, M, w1, b1, w2, b2, (float*)d_out);
}